// Round 10
// baseline (850.567 us; speedup 1.0000x reference)
//
#include <hip/hip_runtime.h>

typedef unsigned short u16;
typedef __attribute__((ext_vector_type(4))) float f32x4;
typedef __attribute__((ext_vector_type(8))) short s16x8;
typedef __attribute__((ext_vector_type(4))) short s16x4;
typedef __attribute__((ext_vector_type(4))) unsigned short u16x4;

#define HH 12
#define CC 768
#define AS1(p) ((const __attribute__((address_space(1))) void*)(p))
#define AS3(p) ((__attribute__((address_space(3))) void*)(p))

__device__ inline u16 f2bf(float x){
  unsigned u = __float_as_uint(x);
  u = (u + 0x7FFFu + ((u >> 16) & 1u)) >> 16;
  return (u16)u;
}

__device__ inline f32x4 mfma32(s16x8 a, s16x8 b, f32x4 c){
  return __builtin_amdgcn_mfma_f32_16x16x32_bf16(a, b, c, 0, 0, 0);
}
__device__ inline f32x4 mfma16(s16x4 a, s16x4 b, f32x4 c){
  return __builtin_amdgcn_mfma_f32_16x16x16bf16_1k(a, b, c, 0, 0, 0);
}

// ---------------- weight fp32 [K,N] -> bf16 [N,K] (per blockIdx.z set) ----------------
__global__ void wtrans(const float* __restrict__ W, u16* __restrict__ Wt, int K, int N){
  __shared__ float tile[32][33];
  int k0 = blockIdx.x*32, n0 = blockIdx.y*32;
  const float* Wz = W + (size_t)blockIdx.z*K*N;
  u16* Wtz = Wt + (size_t)blockIdx.z*K*N;
  int tx = threadIdx.x & 31, ty = threadIdx.x >> 5;
  #pragma unroll
  for(int r = ty; r < 32; r += 8)
    tile[r][tx] = Wz[(size_t)(k0+r)*N + n0 + tx];
  __syncthreads();
  #pragma unroll
  for(int r = ty; r < 32; r += 8)
    Wtz[(size_t)(n0+r)*K + k0 + tx] = f2bf(tile[tx][r]);
}

// ---------------- scatter RGB/NIR/TIR into concat layout [B,387,C] ----------------
__global__ void initcat(const float* __restrict__ R, const float* __restrict__ Nr,
                        const float* __restrict__ T, float* __restrict__ xcat){
  int idx = blockIdx.x*256 + threadIdx.x;
  const int per = 32*129*768/4;
  if(idx >= per) return;
  int z = blockIdx.y;
  const float* src = z == 0 ? R : (z == 1 ? Nr : T);
  float4 v = ((const float4*)src)[idx];
  int e = idx*4;
  int row = e / 768, c = e - row*768;
  int bb2 = row / 129, nn = row - bb2*129;
  ((float4*)xcat)[((size_t)(bb2*387 + z*129 + nn)*768 + c)/4] = v;
}

__device__ inline float maskval(const float* m, int b, int n){
  return (n == 0) ? 1.0f : m[b*128 + n - 1];
}

// ---------------- LayerNorm * mask ----------------
template<int F32OUT>
__global__ __launch_bounds__(64) void ln_mask(
    const float* __restrict__ x,
    const float* __restrict__ gg, const float* __restrict__ bb, int zsG,
    const float* __restrict__ mask,
    void* __restrict__ out, size_t zsO,
    int tpb, int zoffmul)
{
  int r = blockIdx.x, z = blockIdx.y, lane = threadIdx.x;
  int bidx = r / tpb, nn = r - bidx*tpb;
  size_t cat = (size_t)bidx*387 + z*zoffmul + nn;
  const float4* xr = (const float4*)(x + cat*CC);
  float4 v[3]; float s = 0.f, sq = 0.f;
  #pragma unroll
  for(int w = 0; w < 3; ++w){
    v[w] = xr[w*64 + lane];
    s  += v[w].x + v[w].y + v[w].z + v[w].w;
    sq += v[w].x*v[w].x + v[w].y*v[w].y + v[w].z*v[w].z + v[w].w*v[w].w;
  }
  #pragma unroll
  for(int o = 32; o; o >>= 1){ s += __shfl_xor(s, o); sq += __shfl_xor(sq, o); }
  float mu = s * (1.f/768.f);
  float var = sq * (1.f/768.f) - mu*mu;
  float rstd = rsqrtf(var + 1e-5f);
  float mv = maskval(mask, bidx, nn % 129);
  const float4* g4 = (const float4*)(gg + (size_t)z*zsG);
  const float4* b4 = (const float4*)(bb + (size_t)z*zsG);
  #pragma unroll
  for(int w = 0; w < 3; ++w){
    float4 gv = g4[w*64+lane], bv = b4[w*64+lane];
    float y0 = ((v[w].x - mu)*rstd*gv.x + bv.x) * mv;
    float y1 = ((v[w].y - mu)*rstd*gv.y + bv.y) * mv;
    float y2 = ((v[w].z - mu)*rstd*gv.z + bv.z) * mv;
    float y3 = ((v[w].w - mu)*rstd*gv.w + bv.w) * mv;
    if(F32OUT){
      ((float4*)out)[cat*(CC/4) + w*64 + lane] = make_float4(y0,y1,y2,y3);
    } else {
      u16x4 p; p.x = f2bf(y0); p.y = f2bf(y1); p.z = f2bf(y2); p.w = f2bf(y3);
      ((u16x4*)((u16*)out + z*zsO + (size_t)r*CC))[w*64 + lane] = p;
    }
  }
}

// ---------------- GEMM  C[M,N] = A[M,K](bf16) * Bt[N,K](bf16)^T ----------------
// BK=64, dbuf, counted vmcnt; T2 XOR-swizzle (both-sides: inverse-swz global src, swz read).
// Logical LDS L[row][slot8] ; physical P[row][slot ^ (row&7)] ; rows are 128B -> conflict-free.
// EPI 0: store bf16 ; EPI 1: tanh-gelu->bf16 ; EPI 2: += residual into fp32 x_cat
template<int EPI, int TPB>
__global__ __launch_bounds__(256) void gemm_bt(
    const u16* __restrict__ A, size_t zsA,
    const u16* __restrict__ Bt, size_t zsB,
    void* __restrict__ O, size_t zsO,
    int M, int N, int K,
    int zoffmul)
{
  __shared__ u16 As[2][128*64];
  __shared__ u16 Bs[2][128*64];
  int z = blockIdx.z;
  const u16* Az = A + zsA*(size_t)z;
  const u16* Bz = Bt + zsB*(size_t)z;

  // bijective XCD-aware remap (m204)
  int gx = gridDim.x, gy = gridDim.y;
  int nwg = gx*gy;
  int orig = blockIdx.x + gx*blockIdx.y;
  int q = nwg >> 3, r8 = nwg & 7;
  int xcd = orig & 7, off = orig >> 3;
  int wg = (xcd < r8 ? xcd*(q+1) : r8*(q+1) + (xcd-r8)*q) + off;
  int bx = wg / gy, by = wg - bx*gy;
  int m0 = bx*128, n0 = by*128;

  int tid = threadIdx.x, wid = tid >> 6, lane = tid & 63;
  int wr = wid >> 1, wc = wid & 1;
  int lrow = lane & 15, g4 = lane >> 4;

  // ---- staging: thread covers rows (tid>>3)+i*32, 16B slot (tid&7); source col
  // pre-swizzled so linear LDS dest yields P[row][u] = G[row][u^(row&7)].
  int srow = tid >> 3;                         // 0..31
  int swcol = ((tid & 7) ^ (srow & 7)) * 8;    // swizzled source col (elements)
  const u16 *pa[4], *pb[4];
  #pragma unroll
  for(int i = 0; i < 4; ++i){
    int ra = m0 + srow + i*32; ra = ra < M ? ra : M - 1;   // clamp (rows never stored)
    pa[i] = Az + (size_t)ra*K + swcol;
    pb[i] = Bz + (size_t)(n0 + srow + i*32)*K + swcol;
  }
  int dofs = tid*8;                            // linear dest: tid*16B

  auto stage = [&](int b){
    #pragma unroll
    for(int i = 0; i < 4; ++i)
      __builtin_amdgcn_global_load_lds(AS1(pa[i]), AS3(&As[b][dofs + i*2048]), 16, 0, 0);
    #pragma unroll
    for(int i = 0; i < 4; ++i)
      __builtin_amdgcn_global_load_lds(AS1(pb[i]), AS3(&Bs[b][dofs + i*2048]), 16, 0, 0);
    #pragma unroll
    for(int i = 0; i < 4; ++i){ pa[i] += 64; pb[i] += 64; }
  };

  // read-side swizzled slot offsets (elements), per kk-half; row&7 == lrow&7
  int xs0 = ((0*4 + g4) ^ (lrow & 7)) * 8;
  int xs1 = ((1*4 + g4) ^ (lrow & 7)) * 8;

  int NT = K >> 6;
  stage(0);

  f32x4 acc[4][4] = {};
  int cur = 0;

  for(int t = 0; t < NT; ++t){
    if(t + 1 < NT){
      stage(cur ^ 1);
      asm volatile("s_waitcnt vmcnt(8)" ::: "memory");   // tile t's 8 loads done
    } else {
      asm volatile("s_waitcnt vmcnt(0)" ::: "memory");
    }
    __builtin_amdgcn_s_barrier();
    #pragma unroll
    for(int kk = 0; kk < 2; ++kk){
      int xs = kk ? xs1 : xs0;
      s16x8 aF[4], bF[4];
      #pragma unroll
      for(int i = 0; i < 4; ++i){
        aF[i] = *(const s16x8*)&As[cur][(wr*64 + i*16 + lrow)*64 + xs];
        bF[i] = *(const s16x8*)&Bs[cur][(wc*64 + i*16 + lrow)*64 + xs];
      }
      #pragma unroll
      for(int i = 0; i < 4; ++i)
        #pragma unroll
        for(int jn = 0; jn < 4; ++jn)
          acc[i][jn] = mfma32(aF[i], bF[jn], acc[i][jn]);
    }
    __builtin_amdgcn_s_barrier();
    cur ^= 1;
  }

  u16* Oz = (u16*)O + zsO*(size_t)z;
  int zb = z*zoffmul;
  #pragma unroll
  for(int i = 0; i < 4; ++i){
    #pragma unroll
    for(int r = 0; r < 4; ++r){
      int row = m0 + wr*64 + i*16 + g4*4 + r;
      if(row >= M) continue;
      #pragma unroll
      for(int jn = 0; jn < 4; ++jn){
        int col = n0 + wc*64 + jn*16 + lrow;
        float v = acc[i][jn][r];
        if constexpr (EPI == 0){
          Oz[(size_t)row*N + col] = f2bf(v);
        } else if constexpr (EPI == 1){
          float u = v*(0.7978845608f + 0.0356774081f*v*v);
          float t = 1.f - 2.f/(__expf(2.f*u) + 1.f);
          Oz[(size_t)row*N + col] = f2bf(0.5f*v*(1.f + t));
        } else {
          int bi = row / TPB, nnn = row - bi*TPB;
          size_t cat = (size_t)bi*387 + zb + nnn;
          float* dst = (float*)O + cat*CC + col;
          *dst += v;
        }
      }
    }
  }
}

// ---------------- attention v3c: flash-chunked, K/V LDS dbuf; sc redistributed via shfl ----------------
template<int N_>
__global__ __launch_bounds__(256) void attn3(
    const u16* __restrict__ qkv, size_t zsQ,
    u16* __restrict__ out, size_t zsO,
    const float* __restrict__ mask)
{
  constexpr int NC  = (N_ + 63)/64;
  constexpr int NKC = NC*64;
  constexpr float SCL = 0.125f*1.44269504088896f;
  __shared__ u16 Ks[2][64][66];
  __shared__ u16 Vt[2][64][68];
  __shared__ float Msk[NKC];

  int z = blockIdx.z;
  int bh = blockIdx.y, b = bh / HH, hh = bh - b*HH;
  int tid = threadIdx.x, wid = tid >> 6, lane = tid & 63;
  int lq = lane & 15, g = lane >> 4;
  const u16* qz = qkv + zsQ*(size_t)z;
  const size_t rowbase = (size_t)b*N_;
  const u16* kbase = qz + rowbase*2304 + 768 + hh*64;
  const u16* vbase = kbase + 768;

  for(int k = tid; k < NKC; k += 256){
    float mk = 0.f;
    if(k < N_){ int nn = (N_ > 129) ? (k % 129) : k; mk = (nn == 0) ? 1.f : mask[b*128 + nn - 1]; }
    Msk[k] = (mk != 0.f) ? 0.f : -1e30f;
  }

  int q0 = blockIdx.x*64 + wid*16;
  int qrow = q0 + lq;
  int qrc = qrow < N_ ? qrow : N_ - 1;
  const u16* qptr = qz + (rowbase + qrc)*2304 + hh*64;
  s16x8 qF0 = *(const s16x8*)(qptr + g*8);
  s16x8 qF1 = *(const s16x8*)(qptr + 32 + g*8);

  int r0 = tid >> 3, c16 = tid & 7;
  s16x8 kr[2], vr[2];
  const s16x8 zv = {0,0,0,0,0,0,0,0};

  #pragma unroll
  for(int i = 0; i < 2; ++i){
    int row = r0 + i*32;
    kr[i] = (row < N_) ? *(const s16x8*)(kbase + (size_t)row*2304 + c16*8) : zv;
    vr[i] = (row < N_) ? *(const s16x8*)(vbase + (size_t)row*2304 + c16*8) : zv;
  }
  #pragma unroll
  for(int i = 0; i < 2; ++i){
    *(s16x8*)&Ks[0][r0 + i*32][c16*8] = kr[i];
    #pragma unroll
    for(int j = 0; j < 8; ++j) Vt[0][c16*8 + j][r0 + i*32] = (u16)vr[i][j];
  }
  __syncthreads();

  f32x4 o[4] = {};
  float l = 0.f;

  for(int ch = 0; ch < NC; ++ch){
    int cur = ch & 1;
    if(ch + 1 < NC){
      #pragma unroll
      for(int i = 0; i < 2; ++i){
        int row = (ch + 1)*64 + r0 + i*32;
        kr[i] = (row < N_) ? *(const s16x8*)(kbase + (size_t)row*2304 + c16*8) : zv;
        vr[i] = (row < N_) ? *(const s16x8*)(vbase + (size_t)row*2304 + c16*8) : zv;
      }
    }
    float pT[4][4];
    #pragma unroll
    for(int t = 0; t < 4; ++t){
      s16x8 kF0 = *(const s16x8*)&Ks[cur][t*16 + lq][g*8];
      s16x8 kF1 = *(const s16x8*)&Ks[cur][t*16 + lq][32 + g*8];
      f32x4 s = {0.f,0.f,0.f,0.f};
      s = mfma32(kF0, qF0, s);
      s = mfma32(kF1, qF1, s);
      const float* mrow = &Msk[ch*64 + t*16 + g*4];
      #pragma unroll
      for(int r = 0; r < 4; ++r){
        float p = exp2f(fmaf(s[r], SCL, mrow[r]));
        pT[t][r] = p;
        l += p;
      }
    }
    #pragma unroll
    for(int t = 0; t < 4; ++t){
      s16x4 pa;
      #pragma unroll
      for(int r = 0; r < 4; ++r) pa[r] = (short)f2bf(pT[t][r]);
      #pragma unroll
      for(int db = 0; db < 4; ++db){
        s16x4 vf = *(const s16x4*)&Vt[cur][db*16 + lq][t*16 + g*4];
        o[db] = mfma16(pa, vf, o[db]);
      }
    }
    if(ch + 1 < NC){
      int nxt = (ch + 1) & 1;
      #pragma unroll
      for(int i = 0; i < 2; ++i){
        *(s16x8*)&Ks[nxt][r0 + i*32][c16*8] = kr[i];
        #pragma unroll
        for(int j = 0; j < 8; ++j) Vt[nxt][c16*8 + j][r0 + i*32] = (u16)vr[i][j];
      }
      __syncthreads();
    }
  }

  // sc belongs to query lq (P-fragment); output rows are query g*4+r -> shfl redistribute
  l += __shfl_xor(l, 16);
  l += __shfl_xor(l, 32);
  float mq = 0.f;
  if(qrow < N_) mq = (Msk[qrow] == 0.f) ? 1.f : 0.f;
  float sc = mq / l;
  float scr[4];
  #pragma unroll
  for(int r = 0; r < 4; ++r) scr[r] = __shfl(sc, g*4 + r);

  #pragma unroll
  for(int db = 0; db < 4; ++db){
    #pragma unroll
    for(int r = 0; r < 4; ++r){
      int qq = q0 + g*4 + r;
      if(qq < N_)
        out[zsO*(size_t)z + (rowbase + qq)*CC + hh*64 + db*16 + lq] = f2bf(o[db][r]*scr[r]);
    }
  }
}

extern "C" void kernel_launch(void* const* d_in, const int* in_sizes, int n_in,
                              void* d_out, int out_size, void* d_ws, size_t ws_size,
                              hipStream_t stream)
{
  const float* RGB   = (const float*)d_in[0];
  const float* NIR   = (const float*)d_in[1];
  const float* TIR   = (const float*)d_in[2];
  const float* mask  = (const float*)d_in[3];
  const float* ln_g1 = (const float*)d_in[5];
  const float* ln_b1 = (const float*)d_in[6];
  const float* w_qkv = (const float*)d_in[7];
  const float* w_proj= (const float*)d_in[8];
  const float* ln_g2 = (const float*)d_in[9];
  const float* ln_b2 = (const float*)d_in[10];
  const float* w_fc1 = (const float*)d_in[11];
  const float* w_fc2 = (const float*)d_in[12];
  const float* out_g = (const float*)d_in[13];
  const float* out_b = (const float*)d_in[14];

  char* p = (char*)d_ws;
  u16* wqkv_t  = (u16*)p; p += (size_t)4*2304*768*2;
  u16* wproj_t = (u16*)p; p += (size_t)4*768*768*2;
  u16* w1_t    = (u16*)p; p += (size_t)4*768*3072*2;
  u16* w2_t    = (u16*)p; p += (size_t)4*3072*768*2;
  float* xcat  = (float*)p; p += (size_t)12384*768*4;
  u16* xm      = (u16*)p; p += (size_t)3*4224*768*2;
  u16* qkv     = (u16*)p; p += (size_t)3*4224*3072*2;
  u16* hbuf    = qkv;
  if((size_t)(p - (char*)d_ws) > ws_size) return;

  wtrans<<<dim3(24, 72, 4), 256, 0, stream>>>(w_qkv, wqkv_t, 768, 2304);
  wtrans<<<dim3(24, 24, 4), 256, 0, stream>>>(w_proj, wproj_t, 768, 768);
  wtrans<<<dim3(24, 96, 4), 256, 0, stream>>>(w_fc1, w1_t, 768, 3072);
  wtrans<<<dim3(96, 24, 4), 256, 0, stream>>>(w_fc2, w2_t, 3072, 768);
  initcat<<<dim3(3096, 3), 256, 0, stream>>>(RGB, NIR, TIR, xcat);

  const int M3 = 4128;
  const size_t zxm = (size_t)4224*768, zqkv = (size_t)4224*2304, zh = (size_t)4224*3072;
  // ---- branches 0..2 ----
  ln_mask<0><<<dim3(M3,3), 64, 0, stream>>>(xcat, ln_g1, ln_b1, 768, mask, xm, zxm, 129, 129);
  gemm_bt<0,1><<<dim3(33,18,3), 256, 0, stream>>>(xm, zxm, wqkv_t, (size_t)2304*768, qkv, zqkv, M3, 2304, 768, 0);
  attn3<129><<<dim3(3,384,3), 256, 0, stream>>>(qkv, zqkv, xm, zxm, mask);
  gemm_bt<2,129><<<dim3(33,6,3), 256, 0, stream>>>(xm, zxm, wproj_t, (size_t)768*768, xcat, 0, M3, 768, 768, 129);
  ln_mask<0><<<dim3(M3,3), 64, 0, stream>>>(xcat, ln_g2, ln_b2, 768, mask, xm, zxm, 129, 129);
  gemm_bt<1,1><<<dim3(33,24,3), 256, 0, stream>>>(xm, zxm, w1_t, (size_t)768*3072, hbuf, zh, M3, 3072, 768, 0);
  gemm_bt<2,129><<<dim3(33,6,3), 256, 0, stream>>>(hbuf, zh, w2_t, (size_t)768*3072, xcat, 0, M3, 768, 3072, 129);
  // ---- concat branch ----
  const int M1 = 12384;
  ln_mask<0><<<dim3(M1,1), 64, 0, stream>>>(xcat, ln_g1 + 3*768, ln_b1 + 3*768, 0, mask, xm, 0, 387, 0);
  gemm_bt<0,1><<<dim3(97,18,1), 256, 0, stream>>>(xm, 0, wqkv_t + (size_t)3*2304*768, 0, qkv, 0, M1, 2304, 768, 0);
  attn3<387><<<dim3(7,384,1), 256, 0, stream>>>(qkv, 0, xm, 0, mask);
  gemm_bt<2,387><<<dim3(97,6,1), 256, 0, stream>>>(xm, 0, wproj_t + (size_t)3*768*768, 0, xcat, 0, M1, 768, 768, 0);
  ln_mask<0><<<dim3(M1,1), 64, 0, stream>>>(xcat, ln_g2 + 3*768, ln_b2 + 3*768, 0, mask, xm, 0, 387, 0);
  gemm_bt<1,1><<<dim3(97,24,1), 256, 0, stream>>>(xm, 0, w1_t + (size_t)3*768*3072, 0, hbuf, 0, M1, 3072, 768, 0);
  gemm_bt<2,387><<<dim3(97,6,1), 256, 0, stream>>>(hbuf, 0, w2_t + (size_t)3*768*3072, 0, xcat, 0, M1, 768, 3072, 0);
  // ---- final LN ----
  ln_mask<1><<<dim3(M1,1), 64, 0, stream>>>(xcat, out_g, out_b, 0, mask, d_out, 0, 387, 0);
}

// Round 11
// 709.657 us; speedup vs baseline: 1.1986x; 1.1986x over previous
//
#include <hip/hip_runtime.h>

typedef unsigned short u16;
typedef __attribute__((ext_vector_type(4))) float f32x4;
typedef __attribute__((ext_vector_type(8))) short s16x8;
typedef __attribute__((ext_vector_type(4))) short s16x4;
typedef __attribute__((ext_vector_type(4))) unsigned short u16x4;

#define HH 12
#define CC 768
#define AS1(p) ((const __attribute__((address_space(1))) void*)(p))
#define AS3(p) ((__attribute__((address_space(3))) void*)(p))

__device__ inline u16 f2bf(float x){
  unsigned u = __float_as_uint(x);
  u = (u + 0x7FFFu + ((u >> 16) & 1u)) >> 16;
  return (u16)u;
}

__device__ inline f32x4 mfma32(s16x8 a, s16x8 b, f32x4 c){
  return __builtin_amdgcn_mfma_f32_16x16x32_bf16(a, b, c, 0, 0, 0);
}
__device__ inline f32x4 mfma16(s16x4 a, s16x4 b, f32x4 c){
  return __builtin_amdgcn_mfma_f32_16x16x16bf16_1k(a, b, c, 0, 0, 0);
}

// ---------------- weight fp32 [K,N] -> bf16 [N,K] (per blockIdx.z set) ----------------
__global__ void wtrans(const float* __restrict__ W, u16* __restrict__ Wt, int K, int N){
  __shared__ float tile[32][33];
  int k0 = blockIdx.x*32, n0 = blockIdx.y*32;
  const float* Wz = W + (size_t)blockIdx.z*K*N;
  u16* Wtz = Wt + (size_t)blockIdx.z*K*N;
  int tx = threadIdx.x & 31, ty = threadIdx.x >> 5;
  #pragma unroll
  for(int r = ty; r < 32; r += 8)
    tile[r][tx] = Wz[(size_t)(k0+r)*N + n0 + tx];
  __syncthreads();
  #pragma unroll
  for(int r = ty; r < 32; r += 8)
    Wtz[(size_t)(n0+r)*K + k0 + tx] = f2bf(tile[tx][r]);
}

// ---------------- scatter RGB/NIR/TIR into concat layout [B,387,C] ----------------
__global__ void initcat(const float* __restrict__ R, const float* __restrict__ Nr,
                        const float* __restrict__ T, float* __restrict__ xcat){
  int idx = blockIdx.x*256 + threadIdx.x;
  const int per = 32*129*768/4;
  if(idx >= per) return;
  int z = blockIdx.y;
  const float* src = z == 0 ? R : (z == 1 ? Nr : T);
  float4 v = ((const float4*)src)[idx];
  int e = idx*4;
  int row = e / 768, c = e - row*768;
  int bb2 = row / 129, nn = row - bb2*129;
  ((float4*)xcat)[((size_t)(bb2*387 + z*129 + nn)*768 + c)/4] = v;
}

__device__ inline float maskval(const float* m, int b, int n){
  return (n == 0) ? 1.0f : m[b*128 + n - 1];
}

// ---------------- LayerNorm * mask ----------------
template<int F32OUT>
__global__ __launch_bounds__(64) void ln_mask(
    const float* __restrict__ x,
    const float* __restrict__ gg, const float* __restrict__ bb, int zsG,
    const float* __restrict__ mask,
    void* __restrict__ out, size_t zsO,
    int tpb, int zoffmul)
{
  int r = blockIdx.x, z = blockIdx.y, lane = threadIdx.x;
  int bidx = r / tpb, nn = r - bidx*tpb;
  size_t cat = (size_t)bidx*387 + z*zoffmul + nn;
  const float4* xr = (const float4*)(x + cat*CC);
  float4 v[3]; float s = 0.f, sq = 0.f;
  #pragma unroll
  for(int w = 0; w < 3; ++w){
    v[w] = xr[w*64 + lane];
    s  += v[w].x + v[w].y + v[w].z + v[w].w;
    sq += v[w].x*v[w].x + v[w].y*v[w].y + v[w].z*v[w].z + v[w].w*v[w].w;
  }
  #pragma unroll
  for(int o = 32; o; o >>= 1){ s += __shfl_xor(s, o); sq += __shfl_xor(sq, o); }
  float mu = s * (1.f/768.f);
  float var = sq * (1.f/768.f) - mu*mu;
  float rstd = rsqrtf(var + 1e-5f);
  float mv = maskval(mask, bidx, nn % 129);
  const float4* g4 = (const float4*)(gg + (size_t)z*zsG);
  const float4* b4 = (const float4*)(bb + (size_t)z*zsG);
  #pragma unroll
  for(int w = 0; w < 3; ++w){
    float4 gv = g4[w*64+lane], bv = b4[w*64+lane];
    float y0 = ((v[w].x - mu)*rstd*gv.x + bv.x) * mv;
    float y1 = ((v[w].y - mu)*rstd*gv.y + bv.y) * mv;
    float y2 = ((v[w].z - mu)*rstd*gv.z + bv.z) * mv;
    float y3 = ((v[w].w - mu)*rstd*gv.w + bv.w) * mv;
    if(F32OUT){
      ((float4*)out)[cat*(CC/4) + w*64 + lane] = make_float4(y0,y1,y2,y3);
    } else {
      u16x4 p; p.x = f2bf(y0); p.y = f2bf(y1); p.z = f2bf(y2); p.w = f2bf(y3);
      ((u16x4*)((u16*)out + z*zsO + (size_t)r*CC))[w*64 + lane] = p;
    }
  }
}

// ---------------- GEMM  C[M,N] = A[M,K](bf16) * Bt[N,K](bf16)^T ----------------
// Single-buffer BK=64, T2 swizzle (conflict-free), hoisted addrs, 32KB LDS ->
// 4-5 blocks/CU: implicit wave-level overlap (m114) covers the stage drain.
// EPI 0: store bf16 ; EPI 1: tanh-gelu->bf16 ; EPI 2: += residual into fp32 x_cat
template<int EPI, int TPB>
__global__ __launch_bounds__(256, 4) void gemm_bt(
    const u16* __restrict__ A, size_t zsA,
    const u16* __restrict__ Bt, size_t zsB,
    void* __restrict__ O, size_t zsO,
    int M, int N, int K,
    int zoffmul)
{
  __shared__ u16 As[128*64];
  __shared__ u16 Bs[128*64];
  int z = blockIdx.z;
  const u16* Az = A + zsA*(size_t)z;
  const u16* Bz = Bt + zsB*(size_t)z;

  // bijective XCD-aware remap (m204)
  int gx = gridDim.x, gy = gridDim.y;
  int nwg = gx*gy;
  int orig = blockIdx.x + gx*blockIdx.y;
  int q = nwg >> 3, r8 = nwg & 7;
  int xcd = orig & 7, off = orig >> 3;
  int wg = (xcd < r8 ? xcd*(q+1) : r8*(q+1) + (xcd-r8)*q) + off;
  int bx = wg / gy, by = wg - bx*gy;
  int m0 = bx*128, n0 = by*128;

  int tid = threadIdx.x, wid = tid >> 6, lane = tid & 63;
  int wr = wid >> 1, wc = wid & 1;
  int lrow = lane & 15, g4 = lane >> 4;

  // staging: thread covers rows (tid>>3)+i*32, 16B slot (tid&7); source col
  // pre-swizzled so linear LDS dest yields P[row][u] = G[row][u^(row&7)].
  int srow = tid >> 3;
  int swcol = ((tid & 7) ^ (srow & 7)) * 8;
  const u16 *pa[4], *pb[4];
  #pragma unroll
  for(int i = 0; i < 4; ++i){
    int ra = m0 + srow + i*32; ra = ra < M ? ra : M - 1;   // clamp (rows never stored)
    pa[i] = Az + (size_t)ra*K + swcol;
    pb[i] = Bz + (size_t)(n0 + srow + i*32)*K + swcol;
  }
  int dofs = tid*8;   // linear dest: tid*16B

  // read-side swizzled slot offsets (elements); row&7 == lrow&7
  int xs0 = ((0*4 + g4) ^ (lrow & 7)) * 8;
  int xs1 = ((1*4 + g4) ^ (lrow & 7)) * 8;

  f32x4 acc[4][4] = {};
  int NT = K >> 6;

  for(int t = 0; t < NT; ++t){
    #pragma unroll
    for(int i = 0; i < 4; ++i)
      __builtin_amdgcn_global_load_lds(AS1(pa[i]), AS3(&As[dofs + i*2048]), 16, 0, 0);
    #pragma unroll
    for(int i = 0; i < 4; ++i)
      __builtin_amdgcn_global_load_lds(AS1(pb[i]), AS3(&Bs[dofs + i*2048]), 16, 0, 0);
    #pragma unroll
    for(int i = 0; i < 4; ++i){ pa[i] += 64; pb[i] += 64; }
    __syncthreads();   // vmcnt(0)+lgkmcnt drain; other resident blocks cover the gap
    #pragma unroll
    for(int kk = 0; kk < 2; ++kk){
      int xs = kk ? xs1 : xs0;
      s16x8 aF[4], bF[4];
      #pragma unroll
      for(int i = 0; i < 4; ++i){
        aF[i] = *(const s16x8*)&As[(wr*64 + i*16 + lrow)*64 + xs];
        bF[i] = *(const s16x8*)&Bs[(wc*64 + i*16 + lrow)*64 + xs];
      }
      #pragma unroll
      for(int i = 0; i < 4; ++i)
        #pragma unroll
        for(int jn = 0; jn < 4; ++jn)
          acc[i][jn] = mfma32(aF[i], bF[jn], acc[i][jn]);
    }
    __syncthreads();   // reads retired before next stage overwrites
  }

  u16* Oz = (u16*)O + zsO*(size_t)z;
  int zb = z*zoffmul;
  #pragma unroll
  for(int i = 0; i < 4; ++i){
    #pragma unroll
    for(int r = 0; r < 4; ++r){
      int row = m0 + wr*64 + i*16 + g4*4 + r;
      if(row >= M) continue;
      #pragma unroll
      for(int jn = 0; jn < 4; ++jn){
        int col = n0 + wc*64 + jn*16 + lrow;
        float v = acc[i][jn][r];
        if constexpr (EPI == 0){
          Oz[(size_t)row*N + col] = f2bf(v);
        } else if constexpr (EPI == 1){
          float u = v*(0.7978845608f + 0.0356774081f*v*v);
          float t = 1.f - 2.f/(__expf(2.f*u) + 1.f);
          Oz[(size_t)row*N + col] = f2bf(0.5f*v*(1.f + t));
        } else {
          int bi = row / TPB, nnn = row - bi*TPB;
          size_t cat = (size_t)bi*387 + zb + nnn;
          float* dst = (float*)O + cat*CC + col;
          *dst += v;
        }
      }
    }
  }
}

// ---------------- attention v3c: flash-chunked, K/V LDS dbuf; sc redistributed via shfl ----------------
template<int N_>
__global__ __launch_bounds__(256) void attn3(
    const u16* __restrict__ qkv, size_t zsQ,
    u16* __restrict__ out, size_t zsO,
    const float* __restrict__ mask)
{
  constexpr int NC  = (N_ + 63)/64;
  constexpr int NKC = NC*64;
  constexpr float SCL = 0.125f*1.44269504088896f;
  __shared__ u16 Ks[2][64][66];
  __shared__ u16 Vt[2][64][68];
  __shared__ float Msk[NKC];

  int z = blockIdx.z;
  int bh = blockIdx.y, b = bh / HH, hh = bh - b*HH;
  int tid = threadIdx.x, wid = tid >> 6, lane = tid & 63;
  int lq = lane & 15, g = lane >> 4;
  const u16* qz = qkv + zsQ*(size_t)z;
  const size_t rowbase = (size_t)b*N_;
  const u16* kbase = qz + rowbase*2304 + 768 + hh*64;
  const u16* vbase = kbase + 768;

  for(int k = tid; k < NKC; k += 256){
    float mk = 0.f;
    if(k < N_){ int nn = (N_ > 129) ? (k % 129) : k; mk = (nn == 0) ? 1.f : mask[b*128 + nn - 1]; }
    Msk[k] = (mk != 0.f) ? 0.f : -1e30f;
  }

  int q0 = blockIdx.x*64 + wid*16;
  int qrow = q0 + lq;
  int qrc = qrow < N_ ? qrow : N_ - 1;
  const u16* qptr = qz + (rowbase + qrc)*2304 + hh*64;
  s16x8 qF0 = *(const s16x8*)(qptr + g*8);
  s16x8 qF1 = *(const s16x8*)(qptr + 32 + g*8);

  int r0 = tid >> 3, c16 = tid & 7;
  s16x8 kr[2], vr[2];
  const s16x8 zv = {0,0,0,0,0,0,0,0};

  #pragma unroll
  for(int i = 0; i < 2; ++i){
    int row = r0 + i*32;
    kr[i] = (row < N_) ? *(const s16x8*)(kbase + (size_t)row*2304 + c16*8) : zv;
    vr[i] = (row < N_) ? *(const s16x8*)(vbase + (size_t)row*2304 + c16*8) : zv;
  }
  #pragma unroll
  for(int i = 0; i < 2; ++i){
    *(s16x8*)&Ks[0][r0 + i*32][c16*8] = kr[i];
    #pragma unroll
    for(int j = 0; j < 8; ++j) Vt[0][c16*8 + j][r0 + i*32] = (u16)vr[i][j];
  }
  __syncthreads();

  f32x4 o[4] = {};
  float l = 0.f;

  for(int ch = 0; ch < NC; ++ch){
    int cur = ch & 1;
    if(ch + 1 < NC){
      #pragma unroll
      for(int i = 0; i < 2; ++i){
        int row = (ch + 1)*64 + r0 + i*32;
        kr[i] = (row < N_) ? *(const s16x8*)(kbase + (size_t)row*2304 + c16*8) : zv;
        vr[i] = (row < N_) ? *(const s16x8*)(vbase + (size_t)row*2304 + c16*8) : zv;
      }
    }
    float pT[4][4];
    #pragma unroll
    for(int t = 0; t < 4; ++t){
      s16x8 kF0 = *(const s16x8*)&Ks[cur][t*16 + lq][g*8];
      s16x8 kF1 = *(const s16x8*)&Ks[cur][t*16 + lq][32 + g*8];
      f32x4 s = {0.f,0.f,0.f,0.f};
      s = mfma32(kF0, qF0, s);
      s = mfma32(kF1, qF1, s);
      const float* mrow = &Msk[ch*64 + t*16 + g*4];
      #pragma unroll
      for(int r = 0; r < 4; ++r){
        float p = exp2f(fmaf(s[r], SCL, mrow[r]));
        pT[t][r] = p;
        l += p;
      }
    }
    #pragma unroll
    for(int t = 0; t < 4; ++t){
      s16x4 pa;
      #pragma unroll
      for(int r = 0; r < 4; ++r) pa[r] = (short)f2bf(pT[t][r]);
      #pragma unroll
      for(int db = 0; db < 4; ++db){
        s16x4 vf = *(const s16x4*)&Vt[cur][db*16 + lq][t*16 + g*4];
        o[db] = mfma16(pa, vf, o[db]);
      }
    }
    if(ch + 1 < NC){
      int nxt = (ch + 1) & 1;
      #pragma unroll
      for(int i = 0; i < 2; ++i){
        *(s16x8*)&Ks[nxt][r0 + i*32][c16*8] = kr[i];
        #pragma unroll
        for(int j = 0; j < 8; ++j) Vt[nxt][c16*8 + j][r0 + i*32] = (u16)vr[i][j];
      }
      __syncthreads();
    }
  }

  // sc belongs to query lq (P-fragment); output rows are query g*4+r -> shfl redistribute
  l += __shfl_xor(l, 16);
  l += __shfl_xor(l, 32);
  float mq = 0.f;
  if(qrow < N_) mq = (Msk[qrow] == 0.f) ? 1.f : 0.f;
  float sc = mq / l;
  float scr[4];
  #pragma unroll
  for(int r = 0; r < 4; ++r) scr[r] = __shfl(sc, g*4 + r);

  #pragma unroll
  for(int db = 0; db < 4; ++db){
    #pragma unroll
    for(int r = 0; r < 4; ++r){
      int qq = q0 + g*4 + r;
      if(qq < N_)
        out[zsO*(size_t)z + (rowbase + qq)*CC + hh*64 + db*16 + lq] = f2bf(o[db][r]*scr[r]);
    }
  }
}

extern "C" void kernel_launch(void* const* d_in, const int* in_sizes, int n_in,
                              void* d_out, int out_size, void* d_ws, size_t ws_size,
                              hipStream_t stream)
{
  const float* RGB   = (const float*)d_in[0];
  const float* NIR   = (const float*)d_in[1];
  const float* TIR   = (const float*)d_in[2];
  const float* mask  = (const float*)d_in[3];
  const float* ln_g1 = (const float*)d_in[5];
  const float* ln_b1 = (const float*)d_in[6];
  const float* w_qkv = (const float*)d_in[7];
  const float* w_proj= (const float*)d_in[8];
  const float* ln_g2 = (const float*)d_in[9];
  const float* ln_b2 = (const float*)d_in[10];
  const float* w_fc1 = (const float*)d_in[11];
  const float* w_fc2 = (const float*)d_in[12];
  const float* out_g = (const float*)d_in[13];
  const float* out_b = (const float*)d_in[14];

  char* p = (char*)d_ws;
  u16* wqkv_t  = (u16*)p; p += (size_t)4*2304*768*2;
  u16* wproj_t = (u16*)p; p += (size_t)4*768*768*2;
  u16* w1_t    = (u16*)p; p += (size_t)4*768*3072*2;
  u16* w2_t    = (u16*)p; p += (size_t)4*3072*768*2;
  float* xcat  = (float*)p; p += (size_t)12384*768*4;
  u16* xm      = (u16*)p; p += (size_t)3*4224*768*2;
  u16* qkv     = (u16*)p; p += (size_t)3*4224*3072*2;
  u16* hbuf    = qkv;
  if((size_t)(p - (char*)d_ws) > ws_size) return;

  wtrans<<<dim3(24, 72, 4), 256, 0, stream>>>(w_qkv, wqkv_t, 768, 2304);
  wtrans<<<dim3(24, 24, 4), 256, 0, stream>>>(w_proj, wproj_t, 768, 768);
  wtrans<<<dim3(24, 96, 4), 256, 0, stream>>>(w_fc1, w1_t, 768, 3072);
  wtrans<<<dim3(96, 24, 4), 256, 0, stream>>>(w_fc2, w2_t, 3072, 768);
  initcat<<<dim3(3096, 3), 256, 0, stream>>>(RGB, NIR, TIR, xcat);

  const int M3 = 4128;
  const size_t zxm = (size_t)4224*768, zqkv = (size_t)4224*2304, zh = (size_t)4224*3072;
  // ---- branches 0..2 ----
  ln_mask<0><<<dim3(M3,3), 64, 0, stream>>>(xcat, ln_g1, ln_b1, 768, mask, xm, zxm, 129, 129);
  gemm_bt<0,1><<<dim3(33,18,3), 256, 0, stream>>>(xm, zxm, wqkv_t, (size_t)2304*768, qkv, zqkv, M3, 2304, 768, 0);
  attn3<129><<<dim3(3,384,3), 256, 0, stream>>>(qkv, zqkv, xm, zxm, mask);
  gemm_bt<2,129><<<dim3(33,6,3), 256, 0, stream>>>(xm, zxm, wproj_t, (size_t)768*768, xcat, 0, M3, 768, 768, 129);
  ln_mask<0><<<dim3(M3,3), 64, 0, stream>>>(xcat, ln_g2, ln_b2, 768, mask, xm, zxm, 129, 129);
  gemm_bt<1,1><<<dim3(33,24,3), 256, 0, stream>>>(xm, zxm, w1_t, (size_t)768*3072, hbuf, zh, M3, 3072, 768, 0);
  gemm_bt<2,129><<<dim3(33,6,3), 256, 0, stream>>>(hbuf, zh, w2_t, (size_t)768*3072, xcat, 0, M3, 768, 3072, 129);
  // ---- concat branch ----
  const int M1 = 12384;
  ln_mask<0><<<dim3(M1,1), 64, 0, stream>>>(xcat, ln_g1 + 3*768, ln_b1 + 3*768, 0, mask, xm, 0, 387, 0);
  gemm_bt<0,1><<<dim3(97,18,1), 256, 0, stream>>>(xm, 0, wqkv_t + (size_t)3*2304*768, 0, qkv, 0, M1, 2304, 768, 0);
  attn3<387><<<dim3(7,384,1), 256, 0, stream>>>(qkv, 0, xm, 0, mask);
  gemm_bt<2,387><<<dim3(97,6,1), 256, 0, stream>>>(xm, 0, wproj_t + (size_t)3*768*768, 0, xcat, 0, M1, 768, 768, 0);
  ln_mask<0><<<dim3(M1,1), 64, 0, stream>>>(xcat, ln_g2 + 3*768, ln_b2 + 3*768, 0, mask, xm, 0, 387, 0);
  gemm_bt<1,1><<<dim3(97,24,1), 256, 0, stream>>>(xm, 0, w1_t + (size_t)3*768*3072, 0, hbuf, 0, M1, 3072, 768, 0);
  gemm_bt<2,387><<<dim3(97,6,1), 256, 0, stream>>>(hbuf, 0, w2_t + (size_t)3*768*3072, 0, xcat, 0, M1, 768, 3072, 0);
  // ---- final LN ----
  ln_mask<1><<<dim3(M1,1), 64, 0, stream>>>(xcat, out_g, out_b, 0, mask, d_out, 0, 387, 0);
}